// Round 2
// baseline (1108.096 us; speedup 1.0000x reference)
//
#include <hip/hip_runtime.h>

// Fused double-softmax attention, fp32.
// B=4 H=8 S=1024 D=64. Outputs: context [B,H,S,D] then attn [B,H,S,S], fp32.
constexpr int B_ = 4, H_ = 8, S_ = 1024, D_ = 64;
constexpr int BQ = 8;       // q rows per block
constexpr int KT = 128;     // k rows per LDS chunk
constexpr int NT = 512;     // threads per block

__device__ __forceinline__ float wred(float v) {
#pragma unroll
  for (int off = 32; off > 0; off >>= 1) v += __shfl_xor(v, off);
  return v;
}

__global__ __launch_bounds__(NT, 4)   // 4 waves/SIMD -> 2 blocks/CU, VGPR<=128
void fused_attn(const float* __restrict__ Q, const float* __restrict__ K,
                const float* __restrict__ V, const int* __restrict__ mask,
                const float* __restrict__ adj, const float* __restrict__ dist,
                const float* __restrict__ cw, const float* __restrict__ cb,
                float* __restrict__ outC, float* __restrict__ outA)
{
  __shared__ float lQ[BQ][D_];            // 2 KB
  __shared__ float lKV[KT][D_ + 4];       // 34.8 KB
  __shared__ float sc[BQ][S_ + 4];        // 32.9 KB (also reused as reduce scratch)
  __shared__ float apart[8][2];
  __shared__ float rinv1[BQ];
  __shared__ float rinv2[BQ];

  const int tid = threadIdx.x;
  const int qt = blockIdx.x, h = blockIdx.y, b = blockIdx.z;
  const int bh = b * H_ + h;
  const int q0 = qt * BQ;

  const float* Qp = Q + ((size_t)bh * S_ + q0) * D_;
  const float* Kp = K + (size_t)bh * S_ * D_;
  const float* Vp = V + (size_t)bh * S_ * D_;
  const size_t rb = ((size_t)bh * S_ + q0) * S_;

  // load Q tile (8x64 floats = 128 float4)
  if (tid < BQ * D_ / 4) {
    int q = tid >> 4, d4 = (tid & 15) << 2;
    *reinterpret_cast<float4*>(&lQ[q][d4]) =
        *reinterpret_cast<const float4*>(Qp + q * D_ + d4);
  }
  const float w0 = cw[0], w1 = cw[1], w2 = cw[2], bb = cb[0];

  const int wave = tid >> 6;
  const int lane = tid & 63;

  // ===== Phase A: e = exp(QK^T/8), masked -> -1 sentinel. 2 q-rows/thread ====
  const int qg = tid >> 7;          // 0..3
  const int kk = tid & 127;
  const int qa = 2 * qg, qb = 2 * qg + 1;
  float s0 = 0.f, s1 = 0.f;

  for (int c = 0; c < S_ / KT; ++c) {
    __syncthreads();
#pragma unroll
    for (int i = 0; i < (KT * D_ / 4) / NT; ++i) {   // 4 float4 per thread
      int f = tid + NT * i;
      int r = f >> 4, d4 = (f & 15) << 2;
      *reinterpret_cast<float4*>(&lKV[r][d4]) =
          *reinterpret_cast<const float4*>(Kp + (size_t)(c * KT + r) * D_ + d4);
    }
    __syncthreads();

    float a0 = 0.f, a1 = 0.f;
#pragma unroll
    for (int d4 = 0; d4 < D_; d4 += 4) {
      float4 kv = *reinterpret_cast<const float4*>(&lKV[kk][d4]);
      float4 v0 = *reinterpret_cast<const float4*>(&lQ[qa][d4]);
      float4 v1 = *reinterpret_cast<const float4*>(&lQ[qb][d4]);
      a0 += v0.x * kv.x + v0.y * kv.y + v0.z * kv.z + v0.w * kv.w;
      a1 += v1.x * kv.x + v1.y * kv.y + v1.z * kv.z + v1.w * kv.w;
    }
    const int kg = c * KT + kk;
    const int m0 = mask[rb + (size_t)qa * S_ + kg];
    const int m1 = mask[rb + (size_t)qb * S_ + kg];
    float e0 = m0 ? -1.f : __expf(a0 * 0.125f);
    float e1 = m1 ? -1.f : __expf(a1 * 0.125f);
    sc[qa][kg] = e0;
    sc[qb][kg] = e1;
    s0 += m0 ? 0.f : e0;
    s1 += m1 ? 0.f : e1;
  }
  s0 = wred(s0); s1 = wred(s1);
  if (lane == 0) { apart[wave][0] = s0; apart[wave][1] = s1; }
  __syncthreads();
  if (tid < BQ) {
    int g = tid >> 1, sub = tid & 1;
    rinv1[tid] = 1.f / (apart[2 * g][sub] + apart[2 * g + 1][sub]);
  }
  __syncthreads();

  // ===== Phase B: aw = exp(w0*p + w1*dist + w2*adj + b); wave per row ========
  {
    const int q = wave;
    const float i1 = rinv1[q];
    float4 awr[4];
    float s2 = 0.f;
#pragma unroll
    for (int sw = 0; sw < 4; ++sw) {
      const int k4 = sw * 256 + lane * 4;
      float4 e = *reinterpret_cast<const float4*>(&sc[q][k4]);
      float4 dv = *reinterpret_cast<const float4*>(dist + rb + (size_t)q * S_ + k4);
      float4 av = *reinterpret_cast<const float4*>(adj + rb + (size_t)q * S_ + k4);
      float4 aw;
      aw.x = (e.x < 0.f) ? 0.f : __expf(w0 * (e.x * i1) + w1 * dv.x + w2 * av.x + bb);
      aw.y = (e.y < 0.f) ? 0.f : __expf(w0 * (e.y * i1) + w1 * dv.y + w2 * av.y + bb);
      aw.z = (e.z < 0.f) ? 0.f : __expf(w0 * (e.z * i1) + w1 * dv.z + w2 * av.z + bb);
      aw.w = (e.w < 0.f) ? 0.f : __expf(w0 * (e.w * i1) + w1 * dv.w + w2 * av.w + bb);
      *reinterpret_cast<float4*>(&sc[q][k4]) = aw;   // unnormalized, for PV
      awr[sw] = aw;
      s2 += aw.x + aw.y + aw.z + aw.w;
    }
    s2 = wred(s2);                    // all lanes hold total
    const float i2 = 1.f / s2;
    if (lane == 0) rinv2[q] = i2;
#pragma unroll
    for (int sw = 0; sw < 4; ++sw) {  // normalized attn straight from registers
      const int k4 = sw * 256 + lane * 4;
      float4 o = make_float4(awr[sw].x * i2, awr[sw].y * i2,
                             awr[sw].z * i2, awr[sw].w * i2);
      *reinterpret_cast<float4*>(outA + rb + (size_t)q * S_ + k4) = o;
    }
  }

  // ===== Phase C: PV. Thread (d4,ko) accumulates ALL 8 q rows ================
  const int d4c = (tid & 15) << 2;    // d = 4*(tid&15)
  const int ko = tid >> 4;            // 0..31, k subset = 4*ko..4*ko+3 per chunk
  float4 acc[8];
#pragma unroll
  for (int q = 0; q < 8; ++q) acc[q] = make_float4(0.f, 0.f, 0.f, 0.f);

  for (int c = 0; c < S_ / KT; ++c) {
    __syncthreads();
#pragma unroll
    for (int i = 0; i < (KT * D_ / 4) / NT; ++i) {   // stage V chunk
      int f = tid + NT * i;
      int r = f >> 4, d4 = (f & 15) << 2;
      *reinterpret_cast<float4*>(&lKV[r][d4]) =
          *reinterpret_cast<const float4*>(Vp + (size_t)(c * KT + r) * D_ + d4);
    }
    __syncthreads();
    float4 Vr[4];
#pragma unroll
    for (int ki = 0; ki < 4; ++ki)
      Vr[ki] = *reinterpret_cast<const float4*>(&lKV[4 * ko + ki][d4c]);
#pragma unroll
    for (int q = 0; q < 8; ++q) {
      float4 aw = *reinterpret_cast<const float4*>(&sc[q][c * KT + 4 * ko]);
      acc[q].x += aw.x * Vr[0].x + aw.y * Vr[1].x + aw.z * Vr[2].x + aw.w * Vr[3].x;
      acc[q].y += aw.x * Vr[0].y + aw.y * Vr[1].y + aw.z * Vr[2].y + aw.w * Vr[3].y;
      acc[q].z += aw.x * Vr[0].z + aw.y * Vr[1].z + aw.z * Vr[2].z + aw.w * Vr[3].z;
      acc[q].w += aw.x * Vr[0].w + aw.y * Vr[1].w + aw.z * Vr[2].w + aw.w * Vr[3].w;
    }
  }

  // intra-wave reduce over the 4 ko values in this wave (lane bits 4,5)
#pragma unroll
  for (int q = 0; q < 8; ++q) {
    acc[q].x += __shfl_xor(acc[q].x, 16); acc[q].x += __shfl_xor(acc[q].x, 32);
    acc[q].y += __shfl_xor(acc[q].y, 16); acc[q].y += __shfl_xor(acc[q].y, 32);
    acc[q].z += __shfl_xor(acc[q].z, 16); acc[q].z += __shfl_xor(acc[q].z, 32);
    acc[q].w += __shfl_xor(acc[q].w, 16); acc[q].w += __shfl_xor(acc[q].w, 32);
  }
  __syncthreads();                       // all PV reads of sc done
  float4* scratch = reinterpret_cast<float4*>(&sc[0][0]);   // 1024 float4 = 16 KB
  if (lane < 16) {                       // lane == d4 index
#pragma unroll
    for (int q = 0; q < 8; ++q)
      scratch[wave * 128 + q * 16 + lane] = acc[q];
  }
  __syncthreads();
  if (tid < 128) {                       // cross-wave combine + write context
    const int q = tid >> 4, d4 = (tid & 15) << 2;
    float4 s = make_float4(0.f, 0.f, 0.f, 0.f);
#pragma unroll
    for (int w = 0; w < 8; ++w) {
      float4 p = scratch[w * 128 + q * 16 + (tid & 15)];
      s.x += p.x; s.y += p.y; s.z += p.z; s.w += p.w;
    }
    const float i2 = rinv2[q];
    float4 o = make_float4(s.x * i2, s.y * i2, s.z * i2, s.w * i2);
    *reinterpret_cast<float4*>(outC + ((size_t)bh * S_ + q0 + q) * D_ + d4) = o;
  }
}

extern "C" void kernel_launch(void* const* d_in, const int* in_sizes, int n_in,
                              void* d_out, int out_size, void* d_ws, size_t ws_size,
                              hipStream_t stream) {
  const float* Q    = (const float*)d_in[0];
  const float* K    = (const float*)d_in[1];
  const float* V    = (const float*)d_in[2];
  const int*   mask = (const int*)  d_in[3];
  const float* adj  = (const float*)d_in[4];
  const float* dist = (const float*)d_in[5];
  const float* cw   = (const float*)d_in[6];
  const float* cb   = (const float*)d_in[7];

  float* outC = (float*)d_out;                                   // [B,H,S,D]
  float* outA = outC + (size_t)B_ * H_ * S_ * D_;                // [B,H,S,S]

  dim3 grid(S_ / BQ, H_, B_);
  fused_attn<<<grid, NT, 0, stream>>>(Q, K, V, mask, adj, dist, cw, cb, outC, outA);
}

// Round 3
// 693.797 us; speedup vs baseline: 1.5971x; 1.5971x over previous
//
#include <hip/hip_runtime.h>

// Fused double-softmax attention, fp32. B=4 H=8 S=1024 D=64.
// Outputs: context [B,H,S,D] then attn [B,H,S,S], fp32.
constexpr int B_ = 4, H_ = 8, S_ = 1024, D_ = 64;
constexpr int BQ = 16;      // q rows per block
constexpr int NT = 512;     // threads per block
constexpr int SP = S_ + 4;  // sc row stride (pad: bank = (4q+k)%32)

__device__ __forceinline__ float wred(float v) {
#pragma unroll
  for (int off = 32; off > 0; off >>= 1) v += __shfl_xor(v, off);
  return v;
}

__global__ __launch_bounds__(NT, 2)
void fused_attn(const float* __restrict__ Q, const float* __restrict__ K,
                const float* __restrict__ V, const int* __restrict__ mask,
                const float* __restrict__ adj, const float* __restrict__ dist,
                const float* __restrict__ cw, const float* __restrict__ cb,
                float* __restrict__ outC, float* __restrict__ outA)
{
  __shared__ float lQ[BQ][D_];     // 4 KB
  __shared__ float sc[BQ][SP];     // 65.8 KB (reused as reduce scratch at end)
  __shared__ float apart[8][4];
  __shared__ float rinv1[BQ];
  __shared__ float rinv2[BQ];

  const int tid = threadIdx.x;
  // XCD-chunked swizzle: 2048 blocks, XCD x gets a contiguous range (4 heads' K/V -> 2MB in its L2)
  const int sw = (blockIdx.x & 7) * 256 + (blockIdx.x >> 3);
  const int qt = sw & 63;
  const int bh = sw >> 6;
  const int q0 = qt * BQ;

  const float* Qp = Q + ((size_t)bh * S_ + q0) * D_;
  const float* Kp = K + (size_t)bh * S_ * D_;
  const float* Vp = V + (size_t)bh * S_ * D_;
  const size_t rb = ((size_t)bh * S_ + q0) * S_;

  // load Q tile (16x64 = 256 float4)
  if (tid < BQ * D_ / 4) {
    int q = tid >> 4, d4 = (tid & 15) << 2;
    *reinterpret_cast<float4*>(&lQ[q][d4]) =
        *reinterpret_cast<const float4*>(Qp + q * D_ + d4);
  }
  const float w0 = cw[0], w1 = cw[1], w2 = cw[2], bb = cb[0];
  const int wave = tid >> 6;
  const int lane = tid & 63;
  __syncthreads();

  // ===== Phase A: e = exp(QK^T/8), masked -> -1 sentinel =====================
  // thread (qg = tid>>7 owns q rows 4qg..4qg+3, kk = tid&127); 2 k per iter.
  const int qg = tid >> 7;
  const int kk = tid & 127;
  const int qr = 4 * qg;
  float s[4] = {0.f, 0.f, 0.f, 0.f};

  for (int kc = 0; kc < 4; ++kc) {
    const int k0 = kc * 128 + kk;
    const int k1 = k0 + 512;
    const float* Kr0 = Kp + (size_t)k0 * D_;
    const float* Kr1 = Kp + (size_t)k1 * D_;
    float a0[4] = {0.f, 0.f, 0.f, 0.f};
    float a1[4] = {0.f, 0.f, 0.f, 0.f};
#pragma unroll
    for (int d4 = 0; d4 < D_; d4 += 4) {
      const float4 kv0 = *reinterpret_cast<const float4*>(Kr0 + d4);
      const float4 kv1 = *reinterpret_cast<const float4*>(Kr1 + d4);
#pragma unroll
      for (int i = 0; i < 4; ++i) {
        const float4 qv = *reinterpret_cast<const float4*>(&lQ[qr + i][d4]);
        a0[i] += qv.x * kv0.x + qv.y * kv0.y + qv.z * kv0.z + qv.w * kv0.w;
        a1[i] += qv.x * kv1.x + qv.y * kv1.y + qv.z * kv1.z + qv.w * kv1.w;
      }
    }
#pragma unroll
    for (int i = 0; i < 4; ++i) {
      const int m0 = mask[rb + (size_t)(qr + i) * S_ + k0];
      const int m1 = mask[rb + (size_t)(qr + i) * S_ + k1];
      const float e0 = m0 ? -1.f : __expf(a0[i] * 0.125f);
      const float e1 = m1 ? -1.f : __expf(a1[i] * 0.125f);
      sc[qr + i][k0] = e0;
      sc[qr + i][k1] = e1;
      s[i] += (m0 ? 0.f : e0) + (m1 ? 0.f : e1);
    }
  }
#pragma unroll
  for (int i = 0; i < 4; ++i) s[i] = wred(s[i]);
  if (lane == 0) {
#pragma unroll
    for (int i = 0; i < 4; ++i) apart[wave][i] = s[i];
  }
  __syncthreads();
  if (tid < BQ) {
    const int g = tid >> 2, i = tid & 3;
    rinv1[4 * g + i] = 1.f / (apart[2 * g][i] + apart[2 * g + 1][i]);
  }
  __syncthreads();

  // ===== Phase B: aw = exp(w0*p + w1*dist + w2*adj + b); wave per 2 rows =====
  {
    const int qa = 2 * wave, qb = 2 * wave + 1;
    const float i1a = rinv1[qa], i1b = rinv1[qb];
    float s2a = 0.f, s2b = 0.f;
#pragma unroll
    for (int swp = 0; swp < 4; ++swp) {
      const int k4 = swp * 256 + lane * 4;
      {
        float4 e = *reinterpret_cast<const float4*>(&sc[qa][k4]);
        float4 dv = *reinterpret_cast<const float4*>(dist + rb + (size_t)qa * S_ + k4);
        float4 av = *reinterpret_cast<const float4*>(adj + rb + (size_t)qa * S_ + k4);
        float4 aw;
        aw.x = (e.x < 0.f) ? 0.f : __expf(w0 * (e.x * i1a) + w1 * dv.x + w2 * av.x + bb);
        aw.y = (e.y < 0.f) ? 0.f : __expf(w0 * (e.y * i1a) + w1 * dv.y + w2 * av.y + bb);
        aw.z = (e.z < 0.f) ? 0.f : __expf(w0 * (e.z * i1a) + w1 * dv.z + w2 * av.z + bb);
        aw.w = (e.w < 0.f) ? 0.f : __expf(w0 * (e.w * i1a) + w1 * dv.w + w2 * av.w + bb);
        *reinterpret_cast<float4*>(&sc[qa][k4]) = aw;
        s2a += aw.x + aw.y + aw.z + aw.w;
      }
      {
        float4 e = *reinterpret_cast<const float4*>(&sc[qb][k4]);
        float4 dv = *reinterpret_cast<const float4*>(dist + rb + (size_t)qb * S_ + k4);
        float4 av = *reinterpret_cast<const float4*>(adj + rb + (size_t)qb * S_ + k4);
        float4 aw;
        aw.x = (e.x < 0.f) ? 0.f : __expf(w0 * (e.x * i1b) + w1 * dv.x + w2 * av.x + bb);
        aw.y = (e.y < 0.f) ? 0.f : __expf(w0 * (e.y * i1b) + w1 * dv.y + w2 * av.y + bb);
        aw.z = (e.z < 0.f) ? 0.f : __expf(w0 * (e.z * i1b) + w1 * dv.z + w2 * av.z + bb);
        aw.w = (e.w < 0.f) ? 0.f : __expf(w0 * (e.w * i1b) + w1 * dv.w + w2 * av.w + bb);
        *reinterpret_cast<float4*>(&sc[qb][k4]) = aw;
        s2b += aw.x + aw.y + aw.z + aw.w;
      }
    }
    s2a = wred(s2a); s2b = wred(s2b);
    const float i2a = 1.f / s2a, i2b = 1.f / s2b;
    if (lane == 0) { rinv2[qa] = i2a; rinv2[qb] = i2b; }
    // write normalized attn (re-read sc to keep registers low)
#pragma unroll
    for (int swp = 0; swp < 4; ++swp) {
      const int k4 = swp * 256 + lane * 4;
      float4 aa = *reinterpret_cast<const float4*>(&sc[qa][k4]);
      float4 ab = *reinterpret_cast<const float4*>(&sc[qb][k4]);
      float4 oa = make_float4(aa.x * i2a, aa.y * i2a, aa.z * i2a, aa.w * i2a);
      float4 ob = make_float4(ab.x * i2b, ab.y * i2b, ab.z * i2b, ab.w * i2b);
      *reinterpret_cast<float4*>(outA + rb + (size_t)qa * S_ + k4) = oa;
      *reinterpret_cast<float4*>(outA + rb + (size_t)qb * S_ + k4) = ob;
    }
  }
  __syncthreads();

  // ===== Phase C: PV. thread (kq quarter, q pair, d quad), serial over k =====
  const int kq = tid >> 7;            // 0..3 -> k in [256kq, 256kq+256)
  const int qp2 = (tid >> 4) & 7;
  const int d4c = (tid & 15) << 2;
  const int q2a = 2 * qp2, q2b = 2 * qp2 + 1;
  float4 c0 = make_float4(0.f, 0.f, 0.f, 0.f);
  float4 c1 = make_float4(0.f, 0.f, 0.f, 0.f);
  const float* Vq = Vp + (size_t)(kq * 256) * D_ + d4c;
  const int kb = kq * 256;

#pragma unroll 2
  for (int j = 0; j < 256; j += 4) {
    const float4 p0 = *reinterpret_cast<const float4*>(&sc[q2a][kb + j]);
    const float4 p1 = *reinterpret_cast<const float4*>(&sc[q2b][kb + j]);
    const float4 v0 = *reinterpret_cast<const float4*>(Vq + (size_t)(j + 0) * D_);
    const float4 v1 = *reinterpret_cast<const float4*>(Vq + (size_t)(j + 1) * D_);
    const float4 v2 = *reinterpret_cast<const float4*>(Vq + (size_t)(j + 2) * D_);
    const float4 v3 = *reinterpret_cast<const float4*>(Vq + (size_t)(j + 3) * D_);
    c0.x += p0.x * v0.x + p0.y * v1.x + p0.z * v2.x + p0.w * v3.x;
    c0.y += p0.x * v0.y + p0.y * v1.y + p0.z * v2.y + p0.w * v3.y;
    c0.z += p0.x * v0.z + p0.y * v1.z + p0.z * v2.z + p0.w * v3.z;
    c0.w += p0.x * v0.w + p0.y * v1.w + p0.z * v2.w + p0.w * v3.w;
    c1.x += p1.x * v0.x + p1.y * v1.x + p1.z * v2.x + p1.w * v3.x;
    c1.y += p1.x * v0.y + p1.y * v1.y + p1.z * v2.y + p1.w * v3.y;
    c1.z += p1.x * v0.z + p1.y * v1.z + p1.z * v2.z + p1.w * v3.z;
    c1.w += p1.x * v0.w + p1.y * v1.w + p1.z * v2.w + p1.w * v3.w;
  }
  __syncthreads();                       // all PV reads of sc done
  float4* scratch = reinterpret_cast<float4*>(&sc[0][0]);   // 512*2 float4 = 16 KB
  scratch[2 * tid] = c0;
  scratch[2 * tid + 1] = c1;
  __syncthreads();
  if (tid < 128) {                       // kq==0 combines quarters + writes C
    float4 s0 = c0, s1 = c1;
#pragma unroll
    for (int m = 1; m < 4; ++m) {
      float4 p0 = scratch[2 * (tid + 128 * m)];
      float4 p1 = scratch[2 * (tid + 128 * m) + 1];
      s0.x += p0.x; s0.y += p0.y; s0.z += p0.z; s0.w += p0.w;
      s1.x += p1.x; s1.y += p1.y; s1.z += p1.z; s1.w += p1.w;
    }
    const float i2a = rinv2[q2a], i2b = rinv2[q2b];
    float4 o0 = make_float4(s0.x * i2a, s0.y * i2a, s0.z * i2a, s0.w * i2a);
    float4 o1 = make_float4(s1.x * i2b, s1.y * i2b, s1.z * i2b, s1.w * i2b);
    *reinterpret_cast<float4*>(outC + ((size_t)(sw >> 6) * S_ + q0 + q2a) * D_ + d4c) = o0;
    *reinterpret_cast<float4*>(outC + ((size_t)(sw >> 6) * S_ + q0 + q2b) * D_ + d4c) = o1;
  }
}

extern "C" void kernel_launch(void* const* d_in, const int* in_sizes, int n_in,
                              void* d_out, int out_size, void* d_ws, size_t ws_size,
                              hipStream_t stream) {
  const float* Q    = (const float*)d_in[0];
  const float* K    = (const float*)d_in[1];
  const float* V    = (const float*)d_in[2];
  const int*   mask = (const int*)  d_in[3];
  const float* adj  = (const float*)d_in[4];
  const float* dist = (const float*)d_in[5];
  const float* cw   = (const float*)d_in[6];
  const float* cb   = (const float*)d_in[7];

  float* outC = (float*)d_out;                                   // [B,H,S,D]
  float* outA = outC + (size_t)B_ * H_ * S_ * D_;                // [B,H,S,S]

  fused_attn<<<dim3(B_ * H_ * (S_ / BQ)), NT, 0, stream>>>(
      Q, K, V, mask, adj, dist, cw, cb, outC, outA);
}

// Round 4
// 475.724 us; speedup vs baseline: 2.3293x; 1.4584x over previous
//
#include <hip/hip_runtime.h>

// Fused double-softmax attention, fp32. B=4 H=8 S=1024 D=64.
// Outputs: context [B,H,S,D] then attn [B,H,S,S], fp32.
// R4: R1 phase structure / register profile, but K/V read from global
// (L2-resident) instead of LDS staging -> LDS 105KB->70KB -> 2 blocks/CU.
constexpr int B_ = 4, H_ = 8, S_ = 1024, D_ = 64;
constexpr int BQ = 16;      // q rows per block
constexpr int NT = 512;     // threads per block
constexpr int SP = S_ + 4;  // sc row stride (pad)

__device__ __forceinline__ float wred(float v) {
#pragma unroll
  for (int off = 32; off > 0; off >>= 1) v += __shfl_xor(v, off);
  return v;
}

__global__ __launch_bounds__(NT, 2)
void fused_attn(const float* __restrict__ Q, const float* __restrict__ K,
                const float* __restrict__ V, const int* __restrict__ mask,
                const float* __restrict__ adj, const float* __restrict__ dist,
                const float* __restrict__ cw, const float* __restrict__ cb,
                float* __restrict__ outC, float* __restrict__ outA)
{
  __shared__ float lQ[BQ][D_];     // 4 KB
  __shared__ float sc[BQ][SP];     // 65.8 KB (reused as reduce scratch at end)
  __shared__ float apart[8][4];
  __shared__ float rinv1[BQ];
  __shared__ float rinv2[BQ];

  const int tid = threadIdx.x;
  // bijective XCD-chunked swizzle (2048 blocks = 8 XCDs x 256)
  const int sw = (blockIdx.x & 7) * 256 + (blockIdx.x >> 3);
  const int qt = sw & 63;
  const int bh = sw >> 6;
  const int q0 = qt * BQ;

  const float* Qp = Q + ((size_t)bh * S_ + q0) * D_;
  const float* Kp = K + (size_t)bh * S_ * D_;
  const float* Vp = V + (size_t)bh * S_ * D_;
  const size_t rb = ((size_t)bh * S_ + q0) * S_;

  if (tid < BQ * D_ / 4) {          // load Q tile (16x64 = 256 float4)
    int q = tid >> 4, d4 = (tid & 15) << 2;
    *reinterpret_cast<float4*>(&lQ[q][d4]) =
        *reinterpret_cast<const float4*>(Qp + q * D_ + d4);
  }
  const float w0 = cw[0], w1 = cw[1], w2 = cw[2], bb = cb[0];
  const int wave = tid >> 6;
  const int lane = tid & 63;
  __syncthreads();

  // ===== Phase A: e = exp(QK^T/8), masked -> -1 sentinel =====================
  // thread: qg=tid>>7 owns q rows 4qg..4qg+3 (lQ reads broadcast); k=tid&127+128c
  const int qg = tid >> 7;
  const int kk = tid & 127;
  const int qr = 4 * qg;
  float s[4] = {0.f, 0.f, 0.f, 0.f};

  for (int c = 0; c < 8; ++c) {
    const int kg = c * 128 + kk;
    const float* Kr = Kp + (size_t)kg * D_;
    float acc[4] = {0.f, 0.f, 0.f, 0.f};
#pragma unroll 4
    for (int d4 = 0; d4 < D_; d4 += 4) {
      const float4 kv = *reinterpret_cast<const float4*>(Kr + d4);
#pragma unroll
      for (int i = 0; i < 4; ++i) {
        const float4 qv = *reinterpret_cast<const float4*>(&lQ[qr + i][d4]);
        acc[i] += qv.x * kv.x + qv.y * kv.y + qv.z * kv.z + qv.w * kv.w;
      }
    }
#pragma unroll
    for (int i = 0; i < 4; ++i) {
      const int m = mask[rb + (size_t)(qr + i) * S_ + kg];
      const float e = m ? -1.f : __expf(acc[i] * 0.125f);
      sc[qr + i][kg] = e;
      s[i] += m ? 0.f : e;
    }
  }
#pragma unroll
  for (int i = 0; i < 4; ++i) s[i] = wred(s[i]);
  if (lane == 0) {
#pragma unroll
    for (int i = 0; i < 4; ++i) apart[wave][i] = s[i];
  }
  __syncthreads();
  if (tid < BQ) {
    const int g = tid >> 2, i = tid & 3;
    rinv1[4 * g + i] = 1.f / (apart[2 * g][i] + apart[2 * g + 1][i]);
  }
  __syncthreads();

  // ===== Phase B: aw = exp(w0*p + w1*dist + w2*adj + b); wave per 2 rows =====
  {
    const int qa = 2 * wave, qb = 2 * wave + 1;
    const float i1a = rinv1[qa], i1b = rinv1[qb];
    float4 awa[4], awb[4];
    float s2a = 0.f, s2b = 0.f;
#pragma unroll
    for (int swp = 0; swp < 4; ++swp) {
      const int k4 = swp * 256 + lane * 4;
      {
        float4 e = *reinterpret_cast<const float4*>(&sc[qa][k4]);
        float4 dv = *reinterpret_cast<const float4*>(dist + rb + (size_t)qa * S_ + k4);
        float4 av = *reinterpret_cast<const float4*>(adj + rb + (size_t)qa * S_ + k4);
        float4 aw;
        aw.x = (e.x < 0.f) ? 0.f : __expf(w0 * (e.x * i1a) + w1 * dv.x + w2 * av.x + bb);
        aw.y = (e.y < 0.f) ? 0.f : __expf(w0 * (e.y * i1a) + w1 * dv.y + w2 * av.y + bb);
        aw.z = (e.z < 0.f) ? 0.f : __expf(w0 * (e.z * i1a) + w1 * dv.z + w2 * av.z + bb);
        aw.w = (e.w < 0.f) ? 0.f : __expf(w0 * (e.w * i1a) + w1 * dv.w + w2 * av.w + bb);
        *reinterpret_cast<float4*>(&sc[qa][k4]) = aw;
        awa[swp] = aw;
        s2a += aw.x + aw.y + aw.z + aw.w;
      }
      {
        float4 e = *reinterpret_cast<const float4*>(&sc[qb][k4]);
        float4 dv = *reinterpret_cast<const float4*>(dist + rb + (size_t)qb * S_ + k4);
        float4 av = *reinterpret_cast<const float4*>(adj + rb + (size_t)qb * S_ + k4);
        float4 aw;
        aw.x = (e.x < 0.f) ? 0.f : __expf(w0 * (e.x * i1b) + w1 * dv.x + w2 * av.x + bb);
        aw.y = (e.y < 0.f) ? 0.f : __expf(w0 * (e.y * i1b) + w1 * dv.y + w2 * av.y + bb);
        aw.z = (e.z < 0.f) ? 0.f : __expf(w0 * (e.z * i1b) + w1 * dv.z + w2 * av.z + bb);
        aw.w = (e.w < 0.f) ? 0.f : __expf(w0 * (e.w * i1b) + w1 * dv.w + w2 * av.w + bb);
        *reinterpret_cast<float4*>(&sc[qb][k4]) = aw;
        awb[swp] = aw;
        s2b += aw.x + aw.y + aw.z + aw.w;
      }
    }
    s2a = wred(s2a); s2b = wred(s2b);
    const float i2a = 1.f / s2a, i2b = 1.f / s2b;
    if (lane == 0) { rinv2[qa] = i2a; rinv2[qb] = i2b; }
#pragma unroll
    for (int swp = 0; swp < 4; ++swp) {   // normalized attn straight from regs
      const int k4 = swp * 256 + lane * 4;
      float4 oa = make_float4(awa[swp].x * i2a, awa[swp].y * i2a,
                              awa[swp].z * i2a, awa[swp].w * i2a);
      float4 ob = make_float4(awb[swp].x * i2b, awb[swp].y * i2b,
                              awb[swp].z * i2b, awb[swp].w * i2b);
      *reinterpret_cast<float4*>(outA + rb + (size_t)qa * S_ + k4) = oa;
      *reinterpret_cast<float4*>(outA + rb + (size_t)qb * S_ + k4) = ob;
    }
  }
  __syncthreads();

  // ===== Phase C: PV. thread (kq quarter, q pair, d quad), V from global =====
  const int kq = tid >> 7;            // k in [256kq, 256kq+256)
  const int qp2 = (tid >> 4) & 7;
  const int d4c = (tid & 15) << 2;
  const int q2a = 2 * qp2, q2b = 2 * qp2 + 1;
  float4 c0 = make_float4(0.f, 0.f, 0.f, 0.f);
  float4 c1 = make_float4(0.f, 0.f, 0.f, 0.f);
  const float* Vq = Vp + (size_t)(kq * 256) * D_ + d4c;
  const int kb = kq * 256;

#pragma unroll 2
  for (int j = 0; j < 256; j += 4) {
    const float4 p0 = *reinterpret_cast<const float4*>(&sc[q2a][kb + j]);
    const float4 p1 = *reinterpret_cast<const float4*>(&sc[q2b][kb + j]);
    const float4 v0 = *reinterpret_cast<const float4*>(Vq + (size_t)(j + 0) * D_);
    const float4 v1 = *reinterpret_cast<const float4*>(Vq + (size_t)(j + 1) * D_);
    const float4 v2 = *reinterpret_cast<const float4*>(Vq + (size_t)(j + 2) * D_);
    const float4 v3 = *reinterpret_cast<const float4*>(Vq + (size_t)(j + 3) * D_);
    c0.x += p0.x * v0.x + p0.y * v1.x + p0.z * v2.x + p0.w * v3.x;
    c0.y += p0.x * v0.y + p0.y * v1.y + p0.z * v2.y + p0.w * v3.y;
    c0.z += p0.x * v0.z + p0.y * v1.z + p0.z * v2.z + p0.w * v3.z;
    c0.w += p0.x * v0.w + p0.y * v1.w + p0.z * v2.w + p0.w * v3.w;
    c1.x += p1.x * v0.x + p1.y * v1.x + p1.z * v2.x + p1.w * v3.x;
    c1.y += p1.x * v0.y + p1.y * v1.y + p1.z * v2.y + p1.w * v3.y;
    c1.z += p1.x * v0.z + p1.y * v1.z + p1.z * v2.z + p1.w * v3.z;
    c1.w += p1.x * v0.w + p1.y * v1.w + p1.z * v2.w + p1.w * v3.w;
  }
  __syncthreads();                       // all PV reads of sc done
  float4* scratch = reinterpret_cast<float4*>(&sc[0][0]);   // 512*2 float4 = 16 KB
  scratch[2 * tid] = c0;
  scratch[2 * tid + 1] = c1;
  __syncthreads();
  if (tid < 128) {                       // combine k-quarters + write context
    float4 s0 = c0, s1 = c1;
#pragma unroll
    for (int m = 1; m < 4; ++m) {
      float4 p0 = scratch[2 * (tid + 128 * m)];
      float4 p1 = scratch[2 * (tid + 128 * m) + 1];
      s0.x += p0.x; s0.y += p0.y; s0.z += p0.z; s0.w += p0.w;
      s1.x += p1.x; s1.y += p1.y; s1.z += p1.z; s1.w += p1.w;
    }
    const float i2a = rinv2[q2a], i2b = rinv2[q2b];
    float4 o0 = make_float4(s0.x * i2a, s0.y * i2a, s0.z * i2a, s0.w * i2a);
    float4 o1 = make_float4(s1.x * i2b, s1.y * i2b, s1.z * i2b, s1.w * i2b);
    *reinterpret_cast<float4*>(outC + ((size_t)bh * S_ + q0 + q2a) * D_ + d4c) = o0;
    *reinterpret_cast<float4*>(outC + ((size_t)bh * S_ + q0 + q2b) * D_ + d4c) = o1;
  }
}

extern "C" void kernel_launch(void* const* d_in, const int* in_sizes, int n_in,
                              void* d_out, int out_size, void* d_ws, size_t ws_size,
                              hipStream_t stream) {
  const float* Q    = (const float*)d_in[0];
  const float* K    = (const float*)d_in[1];
  const float* V    = (const float*)d_in[2];
  const int*   mask = (const int*)  d_in[3];
  const float* adj  = (const float*)d_in[4];
  const float* dist = (const float*)d_in[5];
  const float* cw   = (const float*)d_in[6];
  const float* cb   = (const float*)d_in[7];

  float* outC = (float*)d_out;                                   // [B,H,S,D]
  float* outA = outC + (size_t)B_ * H_ * S_ * D_;                // [B,H,S,S]

  fused_attn<<<dim3(B_ * H_ * (S_ / BQ)), NT, 0, stream>>>(
      Q, K, V, mask, adj, dist, cw, cb, outC, outA);
}